// Round 8
// baseline (353.301 us; speedup 1.0000x reference)
//
#include <hip/hip_runtime.h>

#define NN 100000   // nodes
#define NE 800000   // edges  (NE % 256 == 0)
#define NG 256      // graphs
#define CH 96       // in/hidden channels
#define OC 16       // out channels
#define NBLK 391    // ceil(NN/256)
#define TM 128      // layer-1 gemm node tile
#define FT 64       // fused kernel node tile
#define RS 100      // Bs row stride in floats (odd float4 count -> benign LDS pattern)

typedef __attribute__((ext_vector_type(8))) short bf16x8;
typedef __attribute__((ext_vector_type(4))) float f32x4;

// ---------------- CSR build ----------------
__global__ __launch_bounds__(256) void k_hist(const int* __restrict__ dst,
                                              int* __restrict__ cnt,
                                              int* __restrict__ slot) {
    int e = blockIdx.x * 256 + threadIdx.x;
    slot[e] = atomicAdd(&cnt[dst[e]], 1);
}

__global__ __launch_bounds__(256) void k_scan1(const int* __restrict__ cnt,
                                               int* __restrict__ off,
                                               int* __restrict__ bsum) {
    __shared__ int sh[256];
    int t = threadIdx.x;
    int i = blockIdx.x * 256 + t;
    int v = (i < NN) ? cnt[i] : 0;
    sh[t] = v;
    __syncthreads();
    for (int d = 1; d < 256; d <<= 1) {
        int x = (t >= d) ? sh[t - d] : 0;
        __syncthreads();
        sh[t] += x;
        __syncthreads();
    }
    if (i < NN) off[i] = sh[t] - v;
    if (t == 255) bsum[blockIdx.x] = sh[255];
}

__global__ __launch_bounds__(512) void k_scan2(int* __restrict__ bsum,
                                               int* __restrict__ boff) {
    __shared__ int sh[512];
    int t = threadIdx.x;
    int v = (t < NBLK) ? bsum[t] : 0;
    sh[t] = v;
    __syncthreads();
    for (int d = 1; d < 512; d <<= 1) {
        int x = (t >= d) ? sh[t - d] : 0;
        __syncthreads();
        sh[t] += x;
        __syncthreads();
    }
    if (t < NBLK) boff[t] = sh[t] - v;
}

__global__ __launch_bounds__(256) void k_scan3(const int* __restrict__ cnt,
                                               int* __restrict__ off,
                                               const int* __restrict__ boff,
                                               float* __restrict__ dinv,
                                               const int* __restrict__ batch,
                                               int* __restrict__ goff) {
    int i = blockIdx.x * 256 + threadIdx.x;
    if (i >= NN) return;
    off[i] += boff[i >> 8];
    dinv[i] = rsqrtf((float)cnt[i] + 1.0f);
    int b = batch[i];
    int bp = (i > 0) ? batch[i - 1] : -1;
    for (int g = bp + 1; g <= b; g++) goff[g] = i;
    if (i == NN - 1)
        for (int g = b + 1; g <= NG; g++) goff[g] = NN;
}

__global__ __launch_bounds__(256) void k_build(const int* __restrict__ src,
                                               const int* __restrict__ dst,
                                               const int* __restrict__ off,
                                               const int* __restrict__ slot,
                                               const float* __restrict__ dinv,
                                               float2* __restrict__ packed) {
    int e = blockIdx.x * 256 + threadIdx.x;
    int s = src[e];
    int d = dst[e];
    packed[off[d] + slot[e]] = make_float2(__int_as_float(s), dinv[s] * dinv[d]);
}

// ---------------- bf16 helpers ----------------
__device__ __forceinline__ unsigned short f2bf(float x) {
    unsigned u = __float_as_uint(x);
    return (unsigned short)((u + 0x7fffu + ((u >> 16) & 1u)) >> 16);  // RNE
}
__device__ __forceinline__ float bf2f(unsigned short h) {
    return __uint_as_float(((unsigned)h) << 16);
}
__device__ __forceinline__ void split8(const float4 a, const float4 b,
                                       bf16x8& hi, bf16x8& lo) {
    float v[8] = {a.x, a.y, a.z, a.w, b.x, b.y, b.z, b.w};
#pragma unroll
    for (int j = 0; j < 8; j++) {
        unsigned short h = f2bf(v[j]);
        hi[j] = (short)h;
        lo[j] = (short)f2bf(v[j] - bf2f(h));
    }
}
__device__ __forceinline__ float4 us4_to_f4(ushort4 u) {
    return make_float4(bf2f(u.x), bf2f(u.y), bf2f(u.z), bf2f(u.w));
}

// ---------------- W prep: 3 weights -> transposed bf16 hi/lo in global ----------------
// WH/WL layout: [w][n][k], row stride 96 ushorts (192 B, 16B-aligned rows)
__global__ __launch_bounds__(256) void k_prep(const float* __restrict__ W1,
                                              const float* __restrict__ W2,
                                              const float* __restrict__ W3,
                                              unsigned short* __restrict__ WH,
                                              unsigned short* __restrict__ WL) {
    int id = blockIdx.x * 256 + threadIdx.x;  // 3*9216 = 27648
    if (id >= 3 * CH * CH) return;
    int w = id / (CH * CH);
    int r = id - w * CH * CH;
    int k = r / CH;
    int n = r - k * CH;
    const float* Ws = (w == 0) ? W1 : (w == 1) ? W2 : W3;
    float v = Ws[k * CH + n];
    unsigned short h = f2bf(v);
    WH[w * CH * CH + n * CH + k] = h;
    WL[w * CH * CH + n * CH + k] = f2bf(v - bf2f(h));
}

// ---------------- layer-1 GEMM: H(bf16) = X(fp32) @ W, W hi/lo from global ----
// 256 threads = 4 waves; wave w owns row-tiles {2w,2w+1} x 6 col-tiles.
__global__ __launch_bounds__(256) void k_gemm96(const float* __restrict__ X,
                                                const unsigned short* __restrict__ WH,
                                                const unsigned short* __restrict__ WL,
                                                unsigned short* __restrict__ H) {
    const int tid = threadIdx.x;
    const int n0 = blockIdx.x * TM;
    const int lane = tid & 63;
    const int wave = tid >> 6;
    const int lrow = lane & 15;
    const int quad = lane >> 4;

    const float4* X4 = reinterpret_cast<const float4*>(X);

    f32x4 acc[2][6];
#pragma unroll
    for (int rt = 0; rt < 2; rt++)
#pragma unroll
        for (int ct = 0; ct < 6; ct++) acc[rt][ct] = (f32x4){0.f, 0.f, 0.f, 0.f};

    int arow[2];
#pragma unroll
    for (int rt = 0; rt < 2; rt++)
        arow[rt] = min(n0 + (wave * 2 + rt) * 16 + lrow, NN - 1);

#pragma unroll
    for (int kc = 0; kc < 3; kc++) {
        bf16x8 ahi[2], alo[2];
#pragma unroll
        for (int rt = 0; rt < 2; rt++) {
            int fo = (arow[rt] * CH + kc * 32 + quad * 8) >> 2;
            split8(X4[fo], X4[fo + 1], ahi[rt], alo[rt]);
        }
#pragma unroll
        for (int ct = 0; ct < 6; ct++) {
            int bo = (ct * 16 + lrow) * CH + kc * 32 + quad * 8;
            bf16x8 bhi = *reinterpret_cast<const bf16x8*>(&WH[bo]);
            bf16x8 blo = *reinterpret_cast<const bf16x8*>(&WL[bo]);
#pragma unroll
            for (int rt = 0; rt < 2; rt++) {
                acc[rt][ct] = __builtin_amdgcn_mfma_f32_16x16x32_bf16(
                    alo[rt], bhi, acc[rt][ct], 0, 0, 0);
                acc[rt][ct] = __builtin_amdgcn_mfma_f32_16x16x32_bf16(
                    ahi[rt], blo, acc[rt][ct], 0, 0, 0);
                acc[rt][ct] = __builtin_amdgcn_mfma_f32_16x16x32_bf16(
                    ahi[rt], bhi, acc[rt][ct], 0, 0, 0);
            }
        }
    }

#pragma unroll
    for (int rt = 0; rt < 2; rt++) {
        int rbase = n0 + (wave * 2 + rt) * 16 + quad * 4;
#pragma unroll
        for (int ct = 0; ct < 6; ct++) {
            int col = ct * 16 + lrow;
#pragma unroll
            for (int r = 0; r < 4; r++) {
                int row = rbase + r;
                if (row < NN) H[(size_t)row * CH + col] = f2bf(acc[rt][ct][r]);
            }
        }
    }
}

// ---------------- fused aggregate_L + gemm_{L+1} ----------------
// Phase A: 64-node tile aggregate (gather from Hin, fp32 accum) -> relu -> LDS Bs.
// Phase B: MFMA Bs (split bf16 hi/lo) @ W -> Hout bf16. Hin != Hout (ping-pong).
__global__ __launch_bounds__(256) void k_fused(const int* __restrict__ off,
                                               const float2* __restrict__ packed,
                                               const float* __restrict__ dinv,
                                               const float* __restrict__ bias,
                                               const unsigned short* __restrict__ Hin,
                                               const unsigned short* __restrict__ WH,
                                               const unsigned short* __restrict__ WL,
                                               unsigned short* __restrict__ Hout) {
    __shared__ __align__(16) float Bs[FT * RS];  // 25.6 KB -> 6 blocks/CU

    const int tid = threadIdx.x;
    const int n0 = blockIdx.x * FT;
    const ushort4* H4 = reinterpret_cast<const ushort4*>(Hin);

    // ---- phase A: aggregate into LDS ----
    for (int it = tid; it < FT * 24; it += 256) {
        int nl = it / 24;
        int c4 = it - nl * 24;
        int n = n0 + nl;
        float4 acc = make_float4(0.f, 0.f, 0.f, 0.f);
        if (n < NN) {
            float di = dinv[n];
            float d2 = di * di;
            float4 h = us4_to_f4(H4[(size_t)n * 24 + c4]);
            float4 bb = reinterpret_cast<const float4*>(bias)[c4];
            acc = make_float4(h.x * d2 + bb.x, h.y * d2 + bb.y,
                              h.z * d2 + bb.z, h.w * d2 + bb.w);
            int e0 = off[n];
            int e1 = (n + 1 < NN) ? off[n + 1] : NE;
            int e = e0;
            for (; e + 4 <= e1; e += 4) {
                float2 p0 = packed[e + 0];
                float2 p1 = packed[e + 1];
                float2 p2 = packed[e + 2];
                float2 p3 = packed[e + 3];
                float4 v0 = us4_to_f4(H4[(size_t)__float_as_int(p0.x) * 24 + c4]);
                float4 v1 = us4_to_f4(H4[(size_t)__float_as_int(p1.x) * 24 + c4]);
                float4 v2 = us4_to_f4(H4[(size_t)__float_as_int(p2.x) * 24 + c4]);
                float4 v3 = us4_to_f4(H4[(size_t)__float_as_int(p3.x) * 24 + c4]);
                acc.x += v0.x * p0.y + v1.x * p1.y + v2.x * p2.y + v3.x * p3.y;
                acc.y += v0.y * p0.y + v1.y * p1.y + v2.y * p2.y + v3.y * p3.y;
                acc.z += v0.z * p0.y + v1.z * p1.y + v2.z * p2.y + v3.z * p3.y;
                acc.w += v0.w * p0.y + v1.w * p1.y + v2.w * p2.y + v3.w * p3.y;
            }
            for (; e < e1; e++) {
                float2 pc = packed[e];
                float4 v = us4_to_f4(H4[(size_t)__float_as_int(pc.x) * 24 + c4]);
                acc.x += v.x * pc.y; acc.y += v.y * pc.y;
                acc.z += v.z * pc.y; acc.w += v.w * pc.y;
            }
            // relu (fused layers are always layers 1/2, both relu)
            acc.x = fmaxf(acc.x, 0.0f); acc.y = fmaxf(acc.y, 0.0f);
            acc.z = fmaxf(acc.z, 0.0f); acc.w = fmaxf(acc.w, 0.0f);
        }
        *reinterpret_cast<float4*>(&Bs[nl * RS + c4 * 4]) = acc;
    }
    __syncthreads();

    // ---- phase B: MFMA Bs @ W -> Hout ----
    const int lane = tid & 63;
    const int wave = tid >> 6;  // row-tile (16 rows each, 4 tiles = 64 rows)
    const int lrow = lane & 15;
    const int quad = lane >> 4;

    f32x4 acc[6];
#pragma unroll
    for (int ct = 0; ct < 6; ct++) acc[ct] = (f32x4){0.f, 0.f, 0.f, 0.f};

    const int abase = (wave * 16 + lrow) * RS;
#pragma unroll
    for (int kc = 0; kc < 3; kc++) {
        const float* ap = &Bs[abase + kc * 32 + quad * 8];
        float4 a0 = *reinterpret_cast<const float4*>(ap);
        float4 a1 = *reinterpret_cast<const float4*>(ap + 4);
        bf16x8 ahi, alo;
        split8(a0, a1, ahi, alo);
#pragma unroll
        for (int ct = 0; ct < 6; ct++) {
            int bo = (ct * 16 + lrow) * CH + kc * 32 + quad * 8;
            bf16x8 bhi = *reinterpret_cast<const bf16x8*>(&WH[bo]);
            bf16x8 blo = *reinterpret_cast<const bf16x8*>(&WL[bo]);
            acc[ct] = __builtin_amdgcn_mfma_f32_16x16x32_bf16(alo, bhi, acc[ct], 0, 0, 0);
            acc[ct] = __builtin_amdgcn_mfma_f32_16x16x32_bf16(ahi, blo, acc[ct], 0, 0, 0);
            acc[ct] = __builtin_amdgcn_mfma_f32_16x16x32_bf16(ahi, bhi, acc[ct], 0, 0, 0);
        }
    }

    int rbase = n0 + wave * 16 + quad * 4;
#pragma unroll
    for (int ct = 0; ct < 6; ct++) {
        int col = ct * 16 + lrow;
#pragma unroll
        for (int r = 0; r < 4; r++) {
            int row = rbase + r;
            if (row < NN) Hout[(size_t)row * CH + col] = f2bf(acc[ct][r]);
        }
    }
}

// ---------------- standalone aggregate (layer 3, no relu, fp32 out) ----------------
__global__ __launch_bounds__(256) void k_aggregate(const int* __restrict__ off,
                                                   const float2* __restrict__ packed,
                                                   const float* __restrict__ dinv,
                                                   const float* __restrict__ bias,
                                                   const unsigned short* __restrict__ H,
                                                   float* __restrict__ B) {
    int idx = blockIdx.x * 256 + threadIdx.x;  // NN*24 exact
    int n = idx / 24;
    int c4 = idx - n * 24;
    int e0 = off[n];
    int e1 = (n + 1 < NN) ? off[n + 1] : NE;

    const ushort4* H4 = reinterpret_cast<const ushort4*>(H);
    float di = dinv[n];
    float d2 = di * di;
    float4 h = us4_to_f4(H4[(size_t)n * 24 + c4]);
    float4 bb = reinterpret_cast<const float4*>(bias)[c4];
    float4 acc = make_float4(h.x * d2 + bb.x, h.y * d2 + bb.y,
                             h.z * d2 + bb.z, h.w * d2 + bb.w);

    int e = e0;
    for (; e + 4 <= e1; e += 4) {
        float2 p0 = packed[e + 0];
        float2 p1 = packed[e + 1];
        float2 p2 = packed[e + 2];
        float2 p3 = packed[e + 3];
        float4 v0 = us4_to_f4(H4[(size_t)__float_as_int(p0.x) * 24 + c4]);
        float4 v1 = us4_to_f4(H4[(size_t)__float_as_int(p1.x) * 24 + c4]);
        float4 v2 = us4_to_f4(H4[(size_t)__float_as_int(p2.x) * 24 + c4]);
        float4 v3 = us4_to_f4(H4[(size_t)__float_as_int(p3.x) * 24 + c4]);
        acc.x += v0.x * p0.y + v1.x * p1.y + v2.x * p2.y + v3.x * p3.y;
        acc.y += v0.y * p0.y + v1.y * p1.y + v2.y * p2.y + v3.y * p3.y;
        acc.z += v0.z * p0.y + v1.z * p1.y + v2.z * p2.y + v3.z * p3.y;
        acc.w += v0.w * p0.y + v1.w * p1.y + v2.w * p2.y + v3.w * p3.y;
    }
    for (; e < e1; e++) {
        float2 pc = packed[e];
        float4 v = us4_to_f4(H4[(size_t)__float_as_int(pc.x) * 24 + c4]);
        acc.x += v.x * pc.y; acc.y += v.y * pc.y;
        acc.z += v.z * pc.y; acc.w += v.w * pc.y;
    }
    reinterpret_cast<float4*>(B)[(size_t)n * 24 + c4] = acc;
}

// ---------------- fused pool + final linear ----------------
__global__ __launch_bounds__(384) void k_pool_linear(const int* __restrict__ goff,
                                                     const float* __restrict__ B,
                                                     const float* __restrict__ Wlin,
                                                     float* __restrict__ out) {
    __shared__ float4 sh[16][24];
    __shared__ float pooled[CH];
    int g = blockIdx.x;
    int t = threadIdx.x;
    int nl = t / 24;
    int c4 = t - nl * 24;
    int s = goff[g];
    int e = goff[g + 1];

    float4 acc = make_float4(0.f, 0.f, 0.f, 0.f);
    const float4* B4 = reinterpret_cast<const float4*>(B);
    for (int n = s + nl; n < e; n += 16) {
        float4 v = B4[(size_t)n * 24 + c4];
        acc.x += v.x; acc.y += v.y; acc.z += v.z; acc.w += v.w;
    }
    sh[nl][c4] = acc;
    __syncthreads();

    if (t < 24) {
        float4 r = make_float4(0.f, 0.f, 0.f, 0.f);
#pragma unroll
        for (int j = 0; j < 16; j++) {
            float4 v = sh[j][t];
            r.x += v.x; r.y += v.y; r.z += v.z; r.w += v.w;
        }
        float inv = 1.0f / fmaxf((float)(e - s), 1.0f);
        pooled[t * 4 + 0] = r.x * inv;
        pooled[t * 4 + 1] = r.y * inv;
        pooled[t * 4 + 2] = r.z * inv;
        pooled[t * 4 + 3] = r.w * inv;
    }
    __syncthreads();

    if (t < OC) {
        float a = 0.0f;
#pragma unroll 8
        for (int k = 0; k < CH; k++) a += pooled[k] * Wlin[k * OC + t];
        out[g * OC + t] = a;
    }
}

// ---------------- launch ----------------
extern "C" void kernel_launch(void* const* d_in, const int* in_sizes, int n_in,
                              void* d_out, int out_size, void* d_ws, size_t ws_size,
                              hipStream_t stream) {
    const float* x = (const float*)d_in[0];
    const int* ei = (const int*)d_in[1];
    const int* src = ei;
    const int* dst = ei + NE;
    const int* batch = (const int*)d_in[2];
    const float* W1 = (const float*)d_in[3];
    const float* b1 = (const float*)d_in[4];
    const float* W2 = (const float*)d_in[5];
    const float* b2 = (const float*)d_in[6];
    const float* W3 = (const float*)d_in[7];
    const float* b3 = (const float*)d_in[8];
    const float* Wlin = (const float*)d_in[9];
    float* out = (float*)d_out;

    char* ws = (char*)d_ws;
    unsigned short* Ha = (unsigned short*)ws;  ws += (size_t)NN * CH * 2;  // 19.2 MB
    unsigned short* Hb = (unsigned short*)ws;  ws += (size_t)NN * CH * 2;  // 19.2 MB
    float* B = (float*)ws;         ws += (size_t)NN * CH * 4;  // 38.4 MB
    float2* packed = (float2*)ws;  ws += (size_t)NE * 8;       // 6.4 MB
    float* dinv = (float*)ws;      ws += NN * 4;
    int* cnt = (int*)ws;           ws += NN * 4;
    int* off = (int*)ws;           ws += NN * 4;
    int* bsum = (int*)ws;          ws += 512 * 4;
    int* boff = (int*)ws;          ws += 512 * 4;
    unsigned short* WH = (unsigned short*)ws;  ws += 3 * CH * CH * 2;  // 55 KB
    unsigned short* WL = (unsigned short*)ws;  ws += 3 * CH * CH * 2;
    int* goff = (int*)ws;          ws += (NG + 1) * 4;
    int* slot = (int*)B;  // B dead until layer-3 aggregate; reuse for edge slots

    // CSR by dst + dinv + graph offsets + W prep
    hipMemsetAsync(cnt, 0, NN * 4, stream);
    k_hist<<<NE / 256, 256, 0, stream>>>(dst, cnt, slot);
    k_scan1<<<NBLK, 256, 0, stream>>>(cnt, off, bsum);
    k_scan2<<<1, 512, 0, stream>>>(bsum, boff);
    k_scan3<<<NBLK, 256, 0, stream>>>(cnt, off, boff, dinv, batch, goff);
    k_build<<<NE / 256, 256, 0, stream>>>(src, dst, off, slot, dinv, packed);
    k_prep<<<(3 * CH * CH + 255) / 256, 256, 0, stream>>>(W1, W2, W3, WH, WL);

    // layer 1 gemm: x -> Ha
    k_gemm96<<<(NN + TM - 1) / TM, 256, 0, stream>>>(x, WH, WL, Ha);
    // fused agg1(relu) + gemm2: Ha -> Hb
    k_fused<<<(NN + FT - 1) / FT, 256, 0, stream>>>(off, packed, dinv, b1, Ha,
                                                    WH + CH * CH, WL + CH * CH, Hb);
    // fused agg2(relu) + gemm3: Hb -> Ha
    k_fused<<<(NN + FT - 1) / FT, 256, 0, stream>>>(off, packed, dinv, b2, Hb,
                                                    WH + 2 * CH * CH, WL + 2 * CH * CH, Ha);
    // layer-3 aggregate (no relu): Ha -> B
    k_aggregate<<<NN * 24 / 256, 256, 0, stream>>>(off, packed, dinv, b3, Ha, B);

    // fused pool + linear
    k_pool_linear<<<NG, 384, 0, stream>>>(goff, B, Wlin, out);
}

// Round 9
// 331.256 us; speedup vs baseline: 1.0666x; 1.0666x over previous
//
#include <hip/hip_runtime.h>

#define NN 100000   // nodes
#define NE 800000   // edges  (NE % 256 == 0)
#define NG 256      // graphs
#define CH 96       // in/hidden channels
#define OC 16       // out channels
#define NBLK 391    // ceil(NN/256)
#define TM 128      // gemm node tile (8 row-tiles of 16)

typedef __attribute__((ext_vector_type(8))) short bf16x8;
typedef __attribute__((ext_vector_type(4))) float f32x4;

// ---------------- bf16 helpers ----------------
__device__ __forceinline__ unsigned short f2bf(float x) {
    unsigned u = __float_as_uint(x);
    return (unsigned short)((u + 0x7fffu + ((u >> 16) & 1u)) >> 16);  // RNE
}
__device__ __forceinline__ float bf2f(unsigned short h) {
    return __uint_as_float(((unsigned)h) << 16);
}
__device__ __forceinline__ void split8(const float4 a, const float4 b,
                                       bf16x8& hi, bf16x8& lo) {
    float v[8] = {a.x, a.y, a.z, a.w, b.x, b.y, b.z, b.w};
#pragma unroll
    for (int j = 0; j < 8; j++) {
        unsigned short h = f2bf(v[j]);
        hi[j] = (short)h;
        lo[j] = (short)f2bf(v[j] - bf2f(h));
    }
}
__device__ __forceinline__ float4 us4_to_f4(ushort4 u) {
    return make_float4(bf2f(u.x), bf2f(u.y), bf2f(u.z), bf2f(u.w));
}

// ---------------- CSR build ----------------
__global__ __launch_bounds__(256) void k_hist(const int* __restrict__ dst,
                                              int* __restrict__ cnt,
                                              int* __restrict__ slot) {
    int e = blockIdx.x * 256 + threadIdx.x;
    slot[e] = atomicAdd(&cnt[dst[e]], 1);
}

// unordered CSR offsets via atomic bump (grouping needs no node order) +
// dinv + graph boundaries, one kernel
__global__ __launch_bounds__(256) void k_offsets(const int* __restrict__ cnt,
                                                 int* __restrict__ gtot,
                                                 int* __restrict__ off,
                                                 float* __restrict__ dinv,
                                                 const int* __restrict__ batch,
                                                 int* __restrict__ goff) {
    int i = blockIdx.x * 256 + threadIdx.x;
    if (i >= NN) return;
    int c = cnt[i];
    off[i] = atomicAdd(gtot, c);
    dinv[i] = rsqrtf((float)c + 1.0f);
    int b = batch[i];
    int bp = (i > 0) ? batch[i - 1] : -1;
    for (int g = bp + 1; g <= b; g++) goff[g] = i;
    if (i == NN - 1)
        for (int g = b + 1; g <= NG; g++) goff[g] = NN;
}

__global__ __launch_bounds__(256) void k_build(const int* __restrict__ src,
                                               const int* __restrict__ dst,
                                               const int* __restrict__ off,
                                               const int* __restrict__ slot,
                                               const float* __restrict__ dinv,
                                               float2* __restrict__ packed) {
    int e = blockIdx.x * 256 + threadIdx.x;
    int s = src[e];
    int d = dst[e];
    packed[off[d] + slot[e]] = make_float2(__int_as_float(s), dinv[s] * dinv[d]);
    if (blockIdx.x == 0 && threadIdx.x < 8)  // valid padding for masked unroll
        packed[NE + threadIdx.x] = make_float2(__int_as_float(0), 0.0f);
}

// ---------------- W prep (once): 3 weights -> transposed bf16 hi/lo ----------------
// WH/WL layout: [w][n][k], row stride CH
__global__ __launch_bounds__(256) void k_prep(const float* __restrict__ W1,
                                              const float* __restrict__ W2,
                                              const float* __restrict__ W3,
                                              unsigned short* __restrict__ WH,
                                              unsigned short* __restrict__ WL) {
    int id = blockIdx.x * 256 + threadIdx.x;  // 3*9216 = 27648
    if (id >= 3 * CH * CH) return;
    int w = id / (CH * CH);
    int r = id - w * CH * CH;
    int k = r / CH;
    int n = r - k * CH;
    const float* Ws = (w == 0) ? W1 : (w == 1) ? W2 : W3;
    float v = Ws[k * CH + n];
    unsigned short h = f2bf(v);
    WH[w * CH * CH + n * CH + k] = h;
    WL[w * CH * CH + n * CH + k] = f2bf(v - bf2f(h));
}

// ---------------- MFMA GEMM: H(bf16) = X(fp32) @ W ----------------
// Stages pre-converted WH/WL (18 KB each) to LDS with plain uint4 copies.
// 256 threads = 4 waves; wave w owns row-tiles {2w,2w+1} x 6 col-tiles.
__global__ __launch_bounds__(256) void k_gemm96(const float* __restrict__ X,
                                                const unsigned short* __restrict__ WH,
                                                const unsigned short* __restrict__ WL,
                                                unsigned short* __restrict__ H) {
    __shared__ __align__(16) unsigned short WsH[CH * CH];  // 18 KB
    __shared__ __align__(16) unsigned short WsL[CH * CH];  // 18 KB

    const int tid = threadIdx.x;
    const int n0 = blockIdx.x * TM;

    {
        const uint4* sH = reinterpret_cast<const uint4*>(WH);
        const uint4* sL = reinterpret_cast<const uint4*>(WL);
        uint4* dH = reinterpret_cast<uint4*>(WsH);
        uint4* dL = reinterpret_cast<uint4*>(WsL);
        for (int i = tid; i < CH * CH / 8; i += 256) {  // 1152 uint4 each
            dH[i] = sH[i];
            dL[i] = sL[i];
        }
    }
    __syncthreads();

    const int lane = tid & 63;
    const int wave = tid >> 6;
    const int lrow = lane & 15;
    const int quad = lane >> 4;

    const float4* X4 = reinterpret_cast<const float4*>(X);

    f32x4 acc[2][6];
#pragma unroll
    for (int rt = 0; rt < 2; rt++)
#pragma unroll
        for (int ct = 0; ct < 6; ct++) acc[rt][ct] = (f32x4){0.f, 0.f, 0.f, 0.f};

    int arow[2];
#pragma unroll
    for (int rt = 0; rt < 2; rt++)
        arow[rt] = min(n0 + (wave * 2 + rt) * 16 + lrow, NN - 1);

#pragma unroll
    for (int kc = 0; kc < 3; kc++) {
        bf16x8 ahi[2], alo[2];
#pragma unroll
        for (int rt = 0; rt < 2; rt++) {
            int fo = (arow[rt] * CH + kc * 32 + quad * 8) >> 2;
            split8(X4[fo], X4[fo + 1], ahi[rt], alo[rt]);
        }
#pragma unroll
        for (int ct = 0; ct < 6; ct++) {
            int bo = (ct * 16 + lrow) * CH + kc * 32 + quad * 8;
            bf16x8 bhi = *reinterpret_cast<const bf16x8*>(&WsH[bo]);
            bf16x8 blo = *reinterpret_cast<const bf16x8*>(&WsL[bo]);
#pragma unroll
            for (int rt = 0; rt < 2; rt++) {
                acc[rt][ct] = __builtin_amdgcn_mfma_f32_16x16x32_bf16(
                    alo[rt], bhi, acc[rt][ct], 0, 0, 0);
                acc[rt][ct] = __builtin_amdgcn_mfma_f32_16x16x32_bf16(
                    ahi[rt], blo, acc[rt][ct], 0, 0, 0);
                acc[rt][ct] = __builtin_amdgcn_mfma_f32_16x16x32_bf16(
                    ahi[rt], bhi, acc[rt][ct], 0, 0, 0);
            }
        }
    }

#pragma unroll
    for (int rt = 0; rt < 2; rt++) {
        int rbase = n0 + (wave * 2 + rt) * 16 + quad * 4;
#pragma unroll
        for (int ct = 0; ct < 6; ct++) {
            int col = ct * 16 + lrow;
#pragma unroll
            for (int r = 0; r < 4; r++) {
                int row = rbase + r;
                if (row < NN) H[(size_t)row * CH + col] = f2bf(acc[rt][ct][r]);
            }
        }
    }
}

// ---------------- per-dst aggregation (no atomics, bf16 gathers) ----------------
// B[n] = (relu?)( H[n]*dinv[n]^2 + b + sum_e coef_e * H[src_e] )
// Fully 4-deep masked loop (packed padded with coef=0 entries at NE..NE+7).
template <bool RELU>
__global__ __launch_bounds__(256) void k_aggregate(const int* __restrict__ off,
                                                   const int* __restrict__ cnt,
                                                   const float2* __restrict__ packed,
                                                   const float* __restrict__ dinv,
                                                   const float* __restrict__ bias,
                                                   const unsigned short* __restrict__ H,
                                                   float* __restrict__ B) {
    int idx = blockIdx.x * 256 + threadIdx.x;  // NN*24 exact
    int n = idx / 24;
    int c4 = idx - n * 24;
    int e0 = off[n];
    int e1 = e0 + cnt[n];

    const ushort4* H4 = reinterpret_cast<const ushort4*>(H);
    float di = dinv[n];
    float d2 = di * di;
    float4 h = us4_to_f4(H4[(size_t)n * 24 + c4]);
    float4 bb = reinterpret_cast<const float4*>(bias)[c4];
    float4 acc = make_float4(h.x * d2 + bb.x, h.y * d2 + bb.y,
                             h.z * d2 + bb.z, h.w * d2 + bb.w);

    for (int e = e0; e < e1; e += 4) {
        float2 p0 = packed[e + 0];
        float2 p1 = packed[e + 1];
        float2 p2 = packed[e + 2];
        float2 p3 = packed[e + 3];
        float c0 = p0.y;
        float c1 = (e + 1 < e1) ? p1.y : 0.0f;
        float c2 = (e + 2 < e1) ? p2.y : 0.0f;
        float c3 = (e + 3 < e1) ? p3.y : 0.0f;
        float4 v0 = us4_to_f4(H4[(size_t)__float_as_int(p0.x) * 24 + c4]);
        float4 v1 = us4_to_f4(H4[(size_t)__float_as_int(p1.x) * 24 + c4]);
        float4 v2 = us4_to_f4(H4[(size_t)__float_as_int(p2.x) * 24 + c4]);
        float4 v3 = us4_to_f4(H4[(size_t)__float_as_int(p3.x) * 24 + c4]);
        acc.x += v0.x * c0 + v1.x * c1 + v2.x * c2 + v3.x * c3;
        acc.y += v0.y * c0 + v1.y * c1 + v2.y * c2 + v3.y * c3;
        acc.z += v0.z * c0 + v1.z * c1 + v2.z * c2 + v3.z * c3;
        acc.w += v0.w * c0 + v1.w * c1 + v2.w * c2 + v3.w * c3;
    }
    if (RELU) {
        acc.x = fmaxf(acc.x, 0.0f); acc.y = fmaxf(acc.y, 0.0f);
        acc.z = fmaxf(acc.z, 0.0f); acc.w = fmaxf(acc.w, 0.0f);
    }
    reinterpret_cast<float4*>(B)[(size_t)n * 24 + c4] = acc;
}

// bf16 output variant used between layers (B feeds next gemm as fp32) — not
// needed; layers use fp32 B. (kept single fp32 version above)

// ---------------- fused pool + final linear ----------------
__global__ __launch_bounds__(384) void k_pool_linear(const int* __restrict__ goff,
                                                     const float* __restrict__ B,
                                                     const float* __restrict__ Wlin,
                                                     float* __restrict__ out) {
    __shared__ float4 sh[16][24];
    __shared__ float pooled[CH];
    int g = blockIdx.x;
    int t = threadIdx.x;
    int nl = t / 24;
    int c4 = t - nl * 24;
    int s = goff[g];
    int e = goff[g + 1];

    float4 acc = make_float4(0.f, 0.f, 0.f, 0.f);
    const float4* B4 = reinterpret_cast<const float4*>(B);
    for (int n = s + nl; n < e; n += 16) {
        float4 v = B4[(size_t)n * 24 + c4];
        acc.x += v.x; acc.y += v.y; acc.z += v.z; acc.w += v.w;
    }
    sh[nl][c4] = acc;
    __syncthreads();

    if (t < 24) {
        float4 r = make_float4(0.f, 0.f, 0.f, 0.f);
#pragma unroll
        for (int j = 0; j < 16; j++) {
            float4 v = sh[j][t];
            r.x += v.x; r.y += v.y; r.z += v.z; r.w += v.w;
        }
        float inv = 1.0f / fmaxf((float)(e - s), 1.0f);
        pooled[t * 4 + 0] = r.x * inv;
        pooled[t * 4 + 1] = r.y * inv;
        pooled[t * 4 + 2] = r.z * inv;
        pooled[t * 4 + 3] = r.w * inv;
    }
    __syncthreads();

    if (t < OC) {
        float a = 0.0f;
#pragma unroll 8
        for (int k = 0; k < CH; k++) a += pooled[k] * Wlin[k * OC + t];
        out[g * OC + t] = a;
    }
}

// ---------------- launch ----------------
extern "C" void kernel_launch(void* const* d_in, const int* in_sizes, int n_in,
                              void* d_out, int out_size, void* d_ws, size_t ws_size,
                              hipStream_t stream) {
    const float* x = (const float*)d_in[0];
    const int* ei = (const int*)d_in[1];
    const int* src = ei;
    const int* dst = ei + NE;
    const int* batch = (const int*)d_in[2];
    const float* W1 = (const float*)d_in[3];
    const float* b1 = (const float*)d_in[4];
    const float* W2 = (const float*)d_in[5];
    const float* b2 = (const float*)d_in[6];
    const float* W3 = (const float*)d_in[7];
    const float* b3 = (const float*)d_in[8];
    const float* Wlin = (const float*)d_in[9];
    float* out = (float*)d_out;

    char* ws = (char*)d_ws;
    unsigned short* Ha = (unsigned short*)ws;  ws += (size_t)NN * CH * 2;  // 19.2 MB
    unsigned short* Hb = (unsigned short*)ws;  ws += (size_t)NN * CH * 2;  // 19.2 MB
    float* B = (float*)ws;          ws += (size_t)NN * CH * 4;   // 38.4 MB
    float2* packed = (float2*)ws;   ws += (size_t)(NE + 8) * 8;  // 6.4 MB (+pad)
    unsigned short* WH = (unsigned short*)ws;  ws += 3 * CH * CH * 2;  // 55 KB
    unsigned short* WL = (unsigned short*)ws;  ws += 3 * CH * CH * 2;
    float* dinv = (float*)ws;       ws += NN * 4;
    int* off = (int*)ws;            ws += NN * 4;
    int* goff = (int*)ws;           ws += 272 * 4;   // NG+1, padded
    int* cnt = (int*)ws;            ws += (NN + 4) * 4;  // +gtot slot
    int* gtot = cnt + NN;
    int* slot = (int*)B;  // B dead until layer-3 aggregate; reuse for edge slots

    // CSR by dst (unordered offsets) + dinv + graph offsets + W prep
    hipMemsetAsync(cnt, 0, (NN + 4) * 4, stream);  // cnt and gtot
    k_hist<<<NE / 256, 256, 0, stream>>>(dst, cnt, slot);
    k_offsets<<<NBLK, 256, 0, stream>>>(cnt, gtot, off, dinv, batch, goff);
    k_build<<<NE / 256, 256, 0, stream>>>(src, dst, off, slot, dinv, packed);
    k_prep<<<(3 * CH * CH + 255) / 256, 256, 0, stream>>>(W1, W2, W3, WH, WL);

    const int gblk = (NN + TM - 1) / TM;

    // layer 1: x -> Ha -> B (relu) ... ping-pong H buffers
    k_gemm96<<<gblk, 256, 0, stream>>>(x, WH, WL, Ha);
    k_aggregate<true><<<NN * 24 / 256, 256, 0, stream>>>(off, cnt, packed, dinv, b1, Ha, B);

    // layer 2: B -> Hb -> B (relu)
    k_gemm96<<<gblk, 256, 0, stream>>>(B, WH + CH * CH, WL + CH * CH, Hb);
    k_aggregate<true><<<NN * 24 / 256, 256, 0, stream>>>(off, cnt, packed, dinv, b2, Hb, B);

    // layer 3: B -> Ha -> B (no relu)
    k_gemm96<<<gblk, 256, 0, stream>>>(B, WH + 2 * CH * CH, WL + 2 * CH * CH, Ha);
    k_aggregate<false><<<NN * 24 / 256, 256, 0, stream>>>(off, cnt, packed, dinv, b3, Ha, B);

    // fused pool + linear
    k_pool_linear<<<NG, 384, 0, stream>>>(goff, B, Wlin, out);
}

// Round 10
// 323.430 us; speedup vs baseline: 1.0924x; 1.0242x over previous
//
#include <hip/hip_runtime.h>

#define NN 100000   // nodes
#define NE 800000   // edges  (NE % 256 == 0)
#define NG 256      // graphs
#define CH 96       // in/hidden channels
#define OC 16       // out channels
#define NBLK 391    // ceil(NN/256)
#define TM 128      // gemm node tile (8 row-tiles of 16)

typedef __attribute__((ext_vector_type(8))) short bf16x8;
typedef __attribute__((ext_vector_type(4))) float f32x4;

// ---------------- bf16 helpers ----------------
__device__ __forceinline__ unsigned short f2bf(float x) {
    unsigned u = __float_as_uint(x);
    return (unsigned short)((u + 0x7fffu + ((u >> 16) & 1u)) >> 16);  // RNE
}
__device__ __forceinline__ float bf2f(unsigned short h) {
    return __uint_as_float(((unsigned)h) << 16);
}
__device__ __forceinline__ void split8(const float4 a, const float4 b,
                                       bf16x8& hi, bf16x8& lo) {
    float v[8] = {a.x, a.y, a.z, a.w, b.x, b.y, b.z, b.w};
#pragma unroll
    for (int j = 0; j < 8; j++) {
        unsigned short h = f2bf(v[j]);
        hi[j] = (short)h;
        lo[j] = (short)f2bf(v[j] - bf2f(h));
    }
}
__device__ __forceinline__ float4 us4_to_f4(ushort4 u) {
    return make_float4(bf2f(u.x), bf2f(u.y), bf2f(u.z), bf2f(u.w));
}

// ---------------- CSR build (+ W prep folded into hist grid) ----------------
// WH/WL layout: [w][n][k], row stride CH
__global__ __launch_bounds__(256) void k_hist(const int* __restrict__ dst,
                                              int* __restrict__ cnt,
                                              int* __restrict__ slot,
                                              const float* __restrict__ W1,
                                              const float* __restrict__ W2,
                                              const float* __restrict__ W3,
                                              unsigned short* __restrict__ WH,
                                              unsigned short* __restrict__ WL) {
    int e = blockIdx.x * 256 + threadIdx.x;
    slot[e] = atomicAdd(&cnt[dst[e]], 1);
    if (e < 3 * CH * CH) {  // fold W-prep into the first 108 blocks
        int w = e / (CH * CH);
        int r = e - w * (CH * CH);
        int k = r / CH;
        int n = r - k * CH;
        const float* Ws = (w == 0) ? W1 : (w == 1) ? W2 : W3;
        float v = Ws[k * CH + n];
        unsigned short h = f2bf(v);
        WH[w * CH * CH + n * CH + k] = h;
        WL[w * CH * CH + n * CH + k] = f2bf(v - bf2f(h));
    }
}

// unordered CSR offsets via atomic bump + dinv + graph boundaries
__global__ __launch_bounds__(256) void k_offsets(const int* __restrict__ cnt,
                                                 int* __restrict__ gtot,
                                                 int* __restrict__ off,
                                                 float* __restrict__ dinv,
                                                 const int* __restrict__ batch,
                                                 int* __restrict__ goff) {
    int i = blockIdx.x * 256 + threadIdx.x;
    if (i >= NN) return;
    int c = cnt[i];
    off[i] = atomicAdd(gtot, c);
    dinv[i] = rsqrtf((float)c + 1.0f);
    int b = batch[i];
    int bp = (i > 0) ? batch[i - 1] : -1;
    for (int g = bp + 1; g <= b; g++) goff[g] = i;
    if (i == NN - 1)
        for (int g = b + 1; g <= NG; g++) goff[g] = NN;
}

__global__ __launch_bounds__(256) void k_build(const int* __restrict__ src,
                                               const int* __restrict__ dst,
                                               const int* __restrict__ off,
                                               const int* __restrict__ slot,
                                               const float* __restrict__ dinv,
                                               float2* __restrict__ packed) {
    int e = blockIdx.x * 256 + threadIdx.x;
    int s = src[e];
    int d = dst[e];
    packed[off[d] + slot[e]] = make_float2(__int_as_float(s), dinv[s] * dinv[d]);
}

// ---------------- MFMA GEMM (layer 1): H(bf16) = X(fp32) @ W ----------------
// X fp32 -> split hi/lo, 3 MFMAs per fragment pair.
__global__ __launch_bounds__(256) void k_gemm_f32(const float* __restrict__ X,
                                                  const unsigned short* __restrict__ WH,
                                                  const unsigned short* __restrict__ WL,
                                                  unsigned short* __restrict__ H) {
    __shared__ __align__(16) unsigned short WsH[CH * CH];  // 18 KB
    __shared__ __align__(16) unsigned short WsL[CH * CH];  // 18 KB

    const int tid = threadIdx.x;
    const int n0 = blockIdx.x * TM;

    {
        const uint4* sH = reinterpret_cast<const uint4*>(WH);
        const uint4* sL = reinterpret_cast<const uint4*>(WL);
        uint4* dH = reinterpret_cast<uint4*>(WsH);
        uint4* dL = reinterpret_cast<uint4*>(WsL);
        for (int i = tid; i < CH * CH / 8; i += 256) {
            dH[i] = sH[i];
            dL[i] = sL[i];
        }
    }
    __syncthreads();

    const int lane = tid & 63;
    const int wave = tid >> 6;
    const int lrow = lane & 15;
    const int quad = lane >> 4;

    const float4* X4 = reinterpret_cast<const float4*>(X);

    f32x4 acc[2][6];
#pragma unroll
    for (int rt = 0; rt < 2; rt++)
#pragma unroll
        for (int ct = 0; ct < 6; ct++) acc[rt][ct] = (f32x4){0.f, 0.f, 0.f, 0.f};

    int arow[2];
#pragma unroll
    for (int rt = 0; rt < 2; rt++)
        arow[rt] = min(n0 + (wave * 2 + rt) * 16 + lrow, NN - 1);

#pragma unroll
    for (int kc = 0; kc < 3; kc++) {
        bf16x8 ahi[2], alo[2];
#pragma unroll
        for (int rt = 0; rt < 2; rt++) {
            int fo = (arow[rt] * CH + kc * 32 + quad * 8) >> 2;
            split8(X4[fo], X4[fo + 1], ahi[rt], alo[rt]);
        }
#pragma unroll
        for (int ct = 0; ct < 6; ct++) {
            int bo = (ct * 16 + lrow) * CH + kc * 32 + quad * 8;
            bf16x8 bhi = *reinterpret_cast<const bf16x8*>(&WsH[bo]);
            bf16x8 blo = *reinterpret_cast<const bf16x8*>(&WsL[bo]);
#pragma unroll
            for (int rt = 0; rt < 2; rt++) {
                acc[rt][ct] = __builtin_amdgcn_mfma_f32_16x16x32_bf16(
                    alo[rt], bhi, acc[rt][ct], 0, 0, 0);
                acc[rt][ct] = __builtin_amdgcn_mfma_f32_16x16x32_bf16(
                    ahi[rt], blo, acc[rt][ct], 0, 0, 0);
                acc[rt][ct] = __builtin_amdgcn_mfma_f32_16x16x32_bf16(
                    ahi[rt], bhi, acc[rt][ct], 0, 0, 0);
            }
        }
    }

#pragma unroll
    for (int rt = 0; rt < 2; rt++) {
        int rbase = n0 + (wave * 2 + rt) * 16 + quad * 4;
#pragma unroll
        for (int ct = 0; ct < 6; ct++) {
            int col = ct * 16 + lrow;
#pragma unroll
            for (int r = 0; r < 4; r++) {
                int row = rbase + r;
                if (row < NN) H[(size_t)row * CH + col] = f2bf(acc[rt][ct][r]);
            }
        }
    }
}

// ---------------- MFMA GEMM (layers 2,3): H(bf16) = X(bf16) @ W ----------------
// A is exact bf16: single b128 A-load, 2 MFMAs (ahi*bhi + ahi*blo).
__global__ __launch_bounds__(256) void k_gemm_bf16(const unsigned short* __restrict__ X,
                                                   const unsigned short* __restrict__ WH,
                                                   const unsigned short* __restrict__ WL,
                                                   unsigned short* __restrict__ H) {
    __shared__ __align__(16) unsigned short WsH[CH * CH];
    __shared__ __align__(16) unsigned short WsL[CH * CH];

    const int tid = threadIdx.x;
    const int n0 = blockIdx.x * TM;

    {
        const uint4* sH = reinterpret_cast<const uint4*>(WH);
        const uint4* sL = reinterpret_cast<const uint4*>(WL);
        uint4* dH = reinterpret_cast<uint4*>(WsH);
        uint4* dL = reinterpret_cast<uint4*>(WsL);
        for (int i = tid; i < CH * CH / 8; i += 256) {
            dH[i] = sH[i];
            dL[i] = sL[i];
        }
    }
    __syncthreads();

    const int lane = tid & 63;
    const int wave = tid >> 6;
    const int lrow = lane & 15;
    const int quad = lane >> 4;

    f32x4 acc[2][6];
#pragma unroll
    for (int rt = 0; rt < 2; rt++)
#pragma unroll
        for (int ct = 0; ct < 6; ct++) acc[rt][ct] = (f32x4){0.f, 0.f, 0.f, 0.f};

    int arow[2];
#pragma unroll
    for (int rt = 0; rt < 2; rt++)
        arow[rt] = min(n0 + (wave * 2 + rt) * 16 + lrow, NN - 1);

#pragma unroll
    for (int kc = 0; kc < 3; kc++) {
        bf16x8 ahi[2];
#pragma unroll
        for (int rt = 0; rt < 2; rt++)
            ahi[rt] = *reinterpret_cast<const bf16x8*>(
                &X[(size_t)arow[rt] * CH + kc * 32 + quad * 8]);
#pragma unroll
        for (int ct = 0; ct < 6; ct++) {
            int bo = (ct * 16 + lrow) * CH + kc * 32 + quad * 8;
            bf16x8 bhi = *reinterpret_cast<const bf16x8*>(&WsH[bo]);
            bf16x8 blo = *reinterpret_cast<const bf16x8*>(&WsL[bo]);
#pragma unroll
            for (int rt = 0; rt < 2; rt++) {
                acc[rt][ct] = __builtin_amdgcn_mfma_f32_16x16x32_bf16(
                    ahi[rt], blo, acc[rt][ct], 0, 0, 0);
                acc[rt][ct] = __builtin_amdgcn_mfma_f32_16x16x32_bf16(
                    ahi[rt], bhi, acc[rt][ct], 0, 0, 0);
            }
        }
    }

#pragma unroll
    for (int rt = 0; rt < 2; rt++) {
        int rbase = n0 + (wave * 2 + rt) * 16 + quad * 4;
#pragma unroll
        for (int ct = 0; ct < 6; ct++) {
            int col = ct * 16 + lrow;
#pragma unroll
            for (int r = 0; r < 4; r++) {
                int row = rbase + r;
                if (row < NN) H[(size_t)row * CH + col] = f2bf(acc[rt][ct][r]);
            }
        }
    }
}

// ---------------- per-dst aggregation (no atomics, bf16 gathers) ----------------
// Bout = (relu?)( H[n]*dinv[n]^2 + b + sum_e coef_e * H[src_e] ); fp32 accum.
// B16OUT: write bf16 (feeds next gemm); else fp32 (feeds pooling).
template <bool RELU, bool B16OUT>
__global__ __launch_bounds__(256) void k_aggregate(const int* __restrict__ off,
                                                   const int* __restrict__ cnt,
                                                   const float2* __restrict__ packed,
                                                   const float* __restrict__ dinv,
                                                   const float* __restrict__ bias,
                                                   const unsigned short* __restrict__ H,
                                                   void* __restrict__ Bout) {
    int idx = blockIdx.x * 256 + threadIdx.x;  // NN*24 exact
    int n = idx / 24;
    int c4 = idx - n * 24;
    int e0 = off[n];
    int e1 = e0 + cnt[n];

    const ushort4* H4 = reinterpret_cast<const ushort4*>(H);
    float di = dinv[n];
    float d2 = di * di;
    float4 h = us4_to_f4(H4[(size_t)n * 24 + c4]);
    float4 bb = reinterpret_cast<const float4*>(bias)[c4];
    float4 acc = make_float4(h.x * d2 + bb.x, h.y * d2 + bb.y,
                             h.z * d2 + bb.z, h.w * d2 + bb.w);

    int e = e0;
    for (; e + 4 <= e1; e += 4) {  // 4 outstanding gathers
        float2 p0 = packed[e + 0];
        float2 p1 = packed[e + 1];
        float2 p2 = packed[e + 2];
        float2 p3 = packed[e + 3];
        float4 v0 = us4_to_f4(H4[(size_t)__float_as_int(p0.x) * 24 + c4]);
        float4 v1 = us4_to_f4(H4[(size_t)__float_as_int(p1.x) * 24 + c4]);
        float4 v2 = us4_to_f4(H4[(size_t)__float_as_int(p2.x) * 24 + c4]);
        float4 v3 = us4_to_f4(H4[(size_t)__float_as_int(p3.x) * 24 + c4]);
        acc.x += v0.x * p0.y + v1.x * p1.y + v2.x * p2.y + v3.x * p3.y;
        acc.y += v0.y * p0.y + v1.y * p1.y + v2.y * p2.y + v3.y * p3.y;
        acc.z += v0.z * p0.y + v1.z * p1.y + v2.z * p2.y + v3.z * p3.y;
        acc.w += v0.w * p0.y + v1.w * p1.y + v2.w * p2.y + v3.w * p3.y;
    }
    for (; e < e1; e++) {
        float2 pc = packed[e];
        float4 v = us4_to_f4(H4[(size_t)__float_as_int(pc.x) * 24 + c4]);
        acc.x += v.x * pc.y; acc.y += v.y * pc.y;
        acc.z += v.z * pc.y; acc.w += v.w * pc.y;
    }
    if (RELU) {
        acc.x = fmaxf(acc.x, 0.0f); acc.y = fmaxf(acc.y, 0.0f);
        acc.z = fmaxf(acc.z, 0.0f); acc.w = fmaxf(acc.w, 0.0f);
    }
    if (B16OUT) {
        ushort4 o;
        o.x = f2bf(acc.x); o.y = f2bf(acc.y); o.z = f2bf(acc.z); o.w = f2bf(acc.w);
        reinterpret_cast<ushort4*>(Bout)[(size_t)n * 24 + c4] = o;
    } else {
        reinterpret_cast<float4*>(Bout)[(size_t)n * 24 + c4] = acc;
    }
}

// ---------------- fused pool + final linear ----------------
__global__ __launch_bounds__(384) void k_pool_linear(const int* __restrict__ goff,
                                                     const float* __restrict__ B,
                                                     const float* __restrict__ Wlin,
                                                     float* __restrict__ out) {
    __shared__ float4 sh[16][24];
    __shared__ float pooled[CH];
    int g = blockIdx.x;
    int t = threadIdx.x;
    int nl = t / 24;
    int c4 = t - nl * 24;
    int s = goff[g];
    int e = goff[g + 1];

    float4 acc = make_float4(0.f, 0.f, 0.f, 0.f);
    const float4* B4 = reinterpret_cast<const float4*>(B);
    for (int n = s + nl; n < e; n += 16) {
        float4 v = B4[(size_t)n * 24 + c4];
        acc.x += v.x; acc.y += v.y; acc.z += v.z; acc.w += v.w;
    }
    sh[nl][c4] = acc;
    __syncthreads();

    if (t < 24) {
        float4 r = make_float4(0.f, 0.f, 0.f, 0.f);
#pragma unroll
        for (int j = 0; j < 16; j++) {
            float4 v = sh[j][t];
            r.x += v.x; r.y += v.y; r.z += v.z; r.w += v.w;
        }
        float inv = 1.0f / fmaxf((float)(e - s), 1.0f);
        pooled[t * 4 + 0] = r.x * inv;
        pooled[t * 4 + 1] = r.y * inv;
        pooled[t * 4 + 2] = r.z * inv;
        pooled[t * 4 + 3] = r.w * inv;
    }
    __syncthreads();

    if (t < OC) {
        float a = 0.0f;
#pragma unroll 8
        for (int k = 0; k < CH; k++) a += pooled[k] * Wlin[k * OC + t];
        out[g * OC + t] = a;
    }
}

// ---------------- launch ----------------
extern "C" void kernel_launch(void* const* d_in, const int* in_sizes, int n_in,
                              void* d_out, int out_size, void* d_ws, size_t ws_size,
                              hipStream_t stream) {
    const float* x = (const float*)d_in[0];
    const int* ei = (const int*)d_in[1];
    const int* src = ei;
    const int* dst = ei + NE;
    const int* batch = (const int*)d_in[2];
    const float* W1 = (const float*)d_in[3];
    const float* b1 = (const float*)d_in[4];
    const float* W2 = (const float*)d_in[5];
    const float* b2 = (const float*)d_in[6];
    const float* W3 = (const float*)d_in[7];
    const float* b3 = (const float*)d_in[8];
    const float* Wlin = (const float*)d_in[9];
    float* out = (float*)d_out;

    char* ws = (char*)d_ws;
    unsigned short* Ha = (unsigned short*)ws;  ws += (size_t)NN * CH * 2;  // 19.2 MB
    unsigned short* Hb = (unsigned short*)ws;  ws += (size_t)NN * CH * 2;  // 19.2 MB
    unsigned short* Bb = (unsigned short*)ws;  ws += (size_t)NN * CH * 2;  // 19.2 MB
    float* B = (float*)ws;          ws += (size_t)NN * CH * 4;   // 38.4 MB
    float2* packed = (float2*)ws;   ws += (size_t)NE * 8;        // 6.4 MB
    unsigned short* WH = (unsigned short*)ws;  ws += 3 * CH * CH * 2;  // 55 KB
    unsigned short* WL = (unsigned short*)ws;  ws += 3 * CH * CH * 2;
    float* dinv = (float*)ws;       ws += NN * 4;
    int* off = (int*)ws;            ws += NN * 4;
    int* goff = (int*)ws;           ws += 272 * 4;       // NG+1, padded
    int* cnt = (int*)ws;            ws += (NN + 4) * 4;  // +gtot slot
    int* gtot = cnt + NN;
    int* slot = (int*)B;  // B dead until layer-3 aggregate; reuse for edge slots

    // CSR build (unordered offsets) + dinv + graph offsets + W prep (folded)
    hipMemsetAsync(cnt, 0, (NN + 4) * 4, stream);
    k_hist<<<NE / 256, 256, 0, stream>>>(dst, cnt, slot, W1, W2, W3, WH, WL);
    k_offsets<<<NBLK, 256, 0, stream>>>(cnt, gtot, off, dinv, batch, goff);
    k_build<<<NE / 256, 256, 0, stream>>>(src, dst, off, slot, dinv, packed);

    const int gblk = (NN + TM - 1) / TM;

    // layer 1: x -> Ha -> Bb(bf16, relu)
    k_gemm_f32<<<gblk, 256, 0, stream>>>(x, WH, WL, Ha);
    k_aggregate<true, true><<<NN * 24 / 256, 256, 0, stream>>>(
        off, cnt, packed, dinv, b1, Ha, Bb);

    // layer 2: Bb -> Hb -> Bb(bf16, relu)
    k_gemm_bf16<<<gblk, 256, 0, stream>>>(Bb, WH + CH * CH, WL + CH * CH, Hb);
    k_aggregate<true, true><<<NN * 24 / 256, 256, 0, stream>>>(
        off, cnt, packed, dinv, b2, Hb, Bb);

    // layer 3: Bb -> Ha -> B(fp32, no relu)
    k_gemm_bf16<<<gblk, 256, 0, stream>>>(Bb, WH + 2 * CH * CH, WL + 2 * CH * CH, Ha);
    k_aggregate<false, false><<<NN * 24 / 256, 256, 0, stream>>>(
        off, cnt, packed, dinv, b3, Ha, B);

    // fused pool + linear
    k_pool_linear<<<NG, 384, 0, stream>>>(goff, B, Wlin, out);
}

// Round 11
// 301.989 us; speedup vs baseline: 1.1699x; 1.0710x over previous
//
#include <hip/hip_runtime.h>

#define NN 100000   // nodes
#define NE 800000   // edges  (NE % 256 == 0)
#define NG 256      // graphs
#define CH 96       // in/hidden channels
#define OC 16       // out channels
#define NBLK 391    // ceil(NN/256)
#define TM 128      // gemm node tile (8 row-tiles of 16)
#define GBLK 782    // ceil(NN/TM)

typedef __attribute__((ext_vector_type(8))) short bf16x8;
typedef __attribute__((ext_vector_type(4))) float f32x4;

// ---------------- bf16 helpers ----------------
__device__ __forceinline__ unsigned short f2bf(float x) {
    unsigned u = __float_as_uint(x);
    return (unsigned short)((u + 0x7fffu + ((u >> 16) & 1u)) >> 16);  // RNE
}
__device__ __forceinline__ float bf2f(unsigned short h) {
    return __uint_as_float(((unsigned)h) << 16);
}
__device__ __forceinline__ void split8(const float4 a, const float4 b,
                                       bf16x8& hi, bf16x8& lo) {
    float v[8] = {a.x, a.y, a.z, a.w, b.x, b.y, b.z, b.w};
#pragma unroll
    for (int j = 0; j < 8; j++) {
        unsigned short h = f2bf(v[j]);
        hi[j] = (short)h;
        lo[j] = (short)f2bf(v[j] - bf2f(h));
    }
}
__device__ __forceinline__ float4 us4_to_f4(ushort4 u) {
    return make_float4(bf2f(u.x), bf2f(u.y), bf2f(u.z), bf2f(u.w));
}
// 4 packed bf16 pairs (uint4) -> 8 floats; element 2k = low half (little endian)
__device__ __forceinline__ void unpack8(uint4 v, float* f) {
    f[0] = __uint_as_float(v.x << 16); f[1] = __uint_as_float(v.x & 0xffff0000u);
    f[2] = __uint_as_float(v.y << 16); f[3] = __uint_as_float(v.y & 0xffff0000u);
    f[4] = __uint_as_float(v.z << 16); f[5] = __uint_as_float(v.z & 0xffff0000u);
    f[6] = __uint_as_float(v.w << 16); f[7] = __uint_as_float(v.w & 0xffff0000u);
}

// ---------------- init: zero cnt/gtot + prep all 3 W -> transposed bf16 hi/lo ----
// WH/WL layout: [w][n][k], row stride CH
__global__ __launch_bounds__(256) void k_init(int* __restrict__ cnt,
                                              const float* __restrict__ W1,
                                              const float* __restrict__ W2,
                                              const float* __restrict__ W3,
                                              unsigned short* __restrict__ WH,
                                              unsigned short* __restrict__ WL) {
    int id = blockIdx.x * 256 + threadIdx.x;
    if (id < NN + 4) cnt[id] = 0;  // cnt + gtot slot
    if (id < 3 * CH * CH) {
        int w = id / (CH * CH);
        int r = id - w * (CH * CH);
        int k = r / CH;
        int n = r - k * CH;
        const float* Ws = (w == 0) ? W1 : (w == 1) ? W2 : W3;
        float v = Ws[k * CH + n];
        unsigned short h = f2bf(v);
        WH[w * CH * CH + n * CH + k] = h;
        WL[w * CH * CH + n * CH + k] = f2bf(v - bf2f(h));
    }
}

// ---------------- front: gemm-1 (blocks < GBLK) + edge histogram (rest) --------
// Independent work merged into one dispatch: hist hides under gemm-1's MFMA.
__global__ __launch_bounds__(256) void k_front(const float* __restrict__ X,
                                               const unsigned short* __restrict__ WH,
                                               const unsigned short* __restrict__ WL,
                                               unsigned short* __restrict__ H,
                                               const int* __restrict__ dst,
                                               int* __restrict__ cnt,
                                               int* __restrict__ slot) {
    __shared__ __align__(16) unsigned short WsH[CH * CH];  // 18 KB
    __shared__ __align__(16) unsigned short WsL[CH * CH];  // 18 KB

    const int tid = threadIdx.x;

    if (blockIdx.x >= GBLK) {  // ---- histogram path ----
        int e = (blockIdx.x - GBLK) * 256 + tid;
        slot[e] = atomicAdd(&cnt[dst[e]], 1);
        return;
    }

    // ---- gemm-1 path: H = X(fp32) @ W1, split-bf16 (3 MFMAs) ----
    const int n0 = blockIdx.x * TM;
    {
        const uint4* sH = reinterpret_cast<const uint4*>(WH);
        const uint4* sL = reinterpret_cast<const uint4*>(WL);
        uint4* dH = reinterpret_cast<uint4*>(WsH);
        uint4* dL = reinterpret_cast<uint4*>(WsL);
        for (int i = tid; i < CH * CH / 8; i += 256) {
            dH[i] = sH[i];
            dL[i] = sL[i];
        }
    }
    __syncthreads();

    const int lane = tid & 63;
    const int wave = tid >> 6;
    const int lrow = lane & 15;
    const int quad = lane >> 4;

    const float4* X4 = reinterpret_cast<const float4*>(X);

    f32x4 acc[2][6];
#pragma unroll
    for (int rt = 0; rt < 2; rt++)
#pragma unroll
        for (int ct = 0; ct < 6; ct++) acc[rt][ct] = (f32x4){0.f, 0.f, 0.f, 0.f};

    int arow[2];
#pragma unroll
    for (int rt = 0; rt < 2; rt++)
        arow[rt] = min(n0 + (wave * 2 + rt) * 16 + lrow, NN - 1);

#pragma unroll
    for (int kc = 0; kc < 3; kc++) {
        bf16x8 ahi[2], alo[2];
#pragma unroll
        for (int rt = 0; rt < 2; rt++) {
            int fo = (arow[rt] * CH + kc * 32 + quad * 8) >> 2;
            split8(X4[fo], X4[fo + 1], ahi[rt], alo[rt]);
        }
#pragma unroll
        for (int ct = 0; ct < 6; ct++) {
            int bo = (ct * 16 + lrow) * CH + kc * 32 + quad * 8;
            bf16x8 bhi = *reinterpret_cast<const bf16x8*>(&WsH[bo]);
            bf16x8 blo = *reinterpret_cast<const bf16x8*>(&WsL[bo]);
#pragma unroll
            for (int rt = 0; rt < 2; rt++) {
                acc[rt][ct] = __builtin_amdgcn_mfma_f32_16x16x32_bf16(
                    alo[rt], bhi, acc[rt][ct], 0, 0, 0);
                acc[rt][ct] = __builtin_amdgcn_mfma_f32_16x16x32_bf16(
                    ahi[rt], blo, acc[rt][ct], 0, 0, 0);
                acc[rt][ct] = __builtin_amdgcn_mfma_f32_16x16x32_bf16(
                    ahi[rt], bhi, acc[rt][ct], 0, 0, 0);
            }
        }
    }

#pragma unroll
    for (int rt = 0; rt < 2; rt++) {
        int rbase = n0 + (wave * 2 + rt) * 16 + quad * 4;
#pragma unroll
        for (int ct = 0; ct < 6; ct++) {
            int col = ct * 16 + lrow;
#pragma unroll
            for (int r = 0; r < 4; r++) {
                int row = rbase + r;
                if (row < NN) H[(size_t)row * CH + col] = f2bf(acc[rt][ct][r]);
            }
        }
    }
}

// unordered CSR offsets via atomic bump + dinv + graph boundaries
__global__ __launch_bounds__(256) void k_offsets(const int* __restrict__ cnt,
                                                 int* __restrict__ gtot,
                                                 int* __restrict__ off,
                                                 float* __restrict__ dinv,
                                                 const int* __restrict__ batch,
                                                 int* __restrict__ goff) {
    int i = blockIdx.x * 256 + threadIdx.x;
    if (i >= NN) return;
    int c = cnt[i];
    off[i] = atomicAdd(gtot, c);
    dinv[i] = rsqrtf((float)c + 1.0f);
    int b = batch[i];
    int bp = (i > 0) ? batch[i - 1] : -1;
    for (int g = bp + 1; g <= b; g++) goff[g] = i;
    if (i == NN - 1)
        for (int g = b + 1; g <= NG; g++) goff[g] = NN;
}

__global__ __launch_bounds__(256) void k_build(const int* __restrict__ src,
                                               const int* __restrict__ dst,
                                               const int* __restrict__ off,
                                               const int* __restrict__ slot,
                                               const float* __restrict__ dinv,
                                               float2* __restrict__ packed) {
    int e = blockIdx.x * 256 + threadIdx.x;
    int s = src[e];
    int d = dst[e];
    packed[off[d] + slot[e]] = make_float2(__int_as_float(s), dinv[s] * dinv[d]);
}

// ---------------- MFMA GEMM (layers 2,3): H(bf16) = X(bf16) @ W ----------------
__global__ __launch_bounds__(256) void k_gemm_bf16(const unsigned short* __restrict__ X,
                                                   const unsigned short* __restrict__ WH,
                                                   const unsigned short* __restrict__ WL,
                                                   unsigned short* __restrict__ H) {
    __shared__ __align__(16) unsigned short WsH[CH * CH];
    __shared__ __align__(16) unsigned short WsL[CH * CH];

    const int tid = threadIdx.x;
    const int n0 = blockIdx.x * TM;

    {
        const uint4* sH = reinterpret_cast<const uint4*>(WH);
        const uint4* sL = reinterpret_cast<const uint4*>(WL);
        uint4* dH = reinterpret_cast<uint4*>(WsH);
        uint4* dL = reinterpret_cast<uint4*>(WsL);
        for (int i = tid; i < CH * CH / 8; i += 256) {
            dH[i] = sH[i];
            dL[i] = sL[i];
        }
    }
    __syncthreads();

    const int lane = tid & 63;
    const int wave = tid >> 6;
    const int lrow = lane & 15;
    const int quad = lane >> 4;

    f32x4 acc[2][6];
#pragma unroll
    for (int rt = 0; rt < 2; rt++)
#pragma unroll
        for (int ct = 0; ct < 6; ct++) acc[rt][ct] = (f32x4){0.f, 0.f, 0.f, 0.f};

    int arow[2];
#pragma unroll
    for (int rt = 0; rt < 2; rt++)
        arow[rt] = min(n0 + (wave * 2 + rt) * 16 + lrow, NN - 1);

#pragma unroll
    for (int kc = 0; kc < 3; kc++) {
        bf16x8 ahi[2];
#pragma unroll
        for (int rt = 0; rt < 2; rt++)
            ahi[rt] = *reinterpret_cast<const bf16x8*>(
                &X[(size_t)arow[rt] * CH + kc * 32 + quad * 8]);
#pragma unroll
        for (int ct = 0; ct < 6; ct++) {
            int bo = (ct * 16 + lrow) * CH + kc * 32 + quad * 8;
            bf16x8 bhi = *reinterpret_cast<const bf16x8*>(&WsH[bo]);
            bf16x8 blo = *reinterpret_cast<const bf16x8*>(&WsL[bo]);
#pragma unroll
            for (int rt = 0; rt < 2; rt++) {
                acc[rt][ct] = __builtin_amdgcn_mfma_f32_16x16x32_bf16(
                    ahi[rt], blo, acc[rt][ct], 0, 0, 0);
                acc[rt][ct] = __builtin_amdgcn_mfma_f32_16x16x32_bf16(
                    ahi[rt], bhi, acc[rt][ct], 0, 0, 0);
            }
        }
    }

#pragma unroll
    for (int rt = 0; rt < 2; rt++) {
        int rbase = n0 + (wave * 2 + rt) * 16 + quad * 4;
#pragma unroll
        for (int ct = 0; ct < 6; ct++) {
            int col = ct * 16 + lrow;
#pragma unroll
            for (int r = 0; r < 4; r++) {
                int row = rbase + r;
                if (row < NN) H[(size_t)row * CH + col] = f2bf(acc[rt][ct][r]);
            }
        }
    }
}

// ---------------- per-dst aggregation: 12 threads/node, 16 B gathers ----------------
// Bout(bf16) = (relu?)( H[n]*dinv[n]^2 + b + sum_e coef_e * H[src_e] ); fp32 accum.
template <bool RELU>
__global__ __launch_bounds__(256) void k_aggregate(const int* __restrict__ off,
                                                   const int* __restrict__ cnt,
                                                   const float2* __restrict__ packed,
                                                   const float* __restrict__ dinv,
                                                   const float* __restrict__ bias,
                                                   const unsigned short* __restrict__ H,
                                                   unsigned short* __restrict__ Bout) {
    int idx = blockIdx.x * 256 + threadIdx.x;  // NN*12
    if (idx >= NN * 12) return;
    int n = idx / 12;
    int c8 = idx - n * 12;  // 8 channels per thread
    int e0 = off[n];
    int e1 = e0 + cnt[n];

    const uint4* H8 = reinterpret_cast<const uint4*>(H);  // 12 x 16B per row

    float a[8];
    {
        float hf[8];
        unpack8(H8[(size_t)n * 12 + c8], hf);
        float di = dinv[n];
        float d2 = di * di;
        const float4* bias4 = reinterpret_cast<const float4*>(bias);
        float4 b0 = bias4[c8 * 2], b1 = bias4[c8 * 2 + 1];
        float bf[8] = {b0.x, b0.y, b0.z, b0.w, b1.x, b1.y, b1.z, b1.w};
#pragma unroll
        for (int j = 0; j < 8; j++) a[j] = hf[j] * d2 + bf[j];
    }

    int e = e0;
    for (; e + 4 <= e1; e += 4) {  // 4 outstanding 16B gathers
        float2 p0 = packed[e + 0];
        float2 p1 = packed[e + 1];
        float2 p2 = packed[e + 2];
        float2 p3 = packed[e + 3];
        uint4 v0 = H8[(size_t)__float_as_int(p0.x) * 12 + c8];
        uint4 v1 = H8[(size_t)__float_as_int(p1.x) * 12 + c8];
        uint4 v2 = H8[(size_t)__float_as_int(p2.x) * 12 + c8];
        uint4 v3 = H8[(size_t)__float_as_int(p3.x) * 12 + c8];
        float f0[8], f1[8], f2[8], f3[8];
        unpack8(v0, f0); unpack8(v1, f1); unpack8(v2, f2); unpack8(v3, f3);
#pragma unroll
        for (int j = 0; j < 8; j++)
            a[j] += f0[j] * p0.y + f1[j] * p1.y + f2[j] * p2.y + f3[j] * p3.y;
    }
    for (; e < e1; e++) {
        float2 pc = packed[e];
        uint4 v = H8[(size_t)__float_as_int(pc.x) * 12 + c8];
        float f[8];
        unpack8(v, f);
#pragma unroll
        for (int j = 0; j < 8; j++) a[j] += f[j] * pc.y;
    }
    if (RELU) {
#pragma unroll
        for (int j = 0; j < 8; j++) a[j] = fmaxf(a[j], 0.0f);
    }
    uint4 o;
    o.x = (unsigned)f2bf(a[0]) | ((unsigned)f2bf(a[1]) << 16);
    o.y = (unsigned)f2bf(a[2]) | ((unsigned)f2bf(a[3]) << 16);
    o.z = (unsigned)f2bf(a[4]) | ((unsigned)f2bf(a[5]) << 16);
    o.w = (unsigned)f2bf(a[6]) | ((unsigned)f2bf(a[7]) << 16);
    reinterpret_cast<uint4*>(Bout)[(size_t)n * 12 + c8] = o;
}

// ---------------- fused pool + final linear (bf16 input) ----------------
__global__ __launch_bounds__(384) void k_pool_linear(const int* __restrict__ goff,
                                                     const unsigned short* __restrict__ B,
                                                     const float* __restrict__ Wlin,
                                                     float* __restrict__ out) {
    __shared__ float4 sh[16][24];
    __shared__ float pooled[CH];
    int g = blockIdx.x;
    int t = threadIdx.x;
    int nl = t / 24;
    int c4 = t - nl * 24;
    int s = goff[g];
    int e = goff[g + 1];

    float4 acc = make_float4(0.f, 0.f, 0.f, 0.f);
    const ushort4* B4 = reinterpret_cast<const ushort4*>(B);
    for (int n = s + nl; n < e; n += 16) {
        float4 v = us4_to_f4(B4[(size_t)n * 24 + c4]);
        acc.x += v.x; acc.y += v.y; acc.z += v.z; acc.w += v.w;
    }
    sh[nl][c4] = acc;
    __syncthreads();

    if (t < 24) {
        float4 r = make_float4(0.f, 0.f, 0.f, 0.f);
#pragma unroll
        for (int j = 0; j < 16; j++) {
            float4 v = sh[j][t];
            r.x += v.x; r.y += v.y; r.z += v.z; r.w += v.w;
        }
        float inv = 1.0f / fmaxf((float)(e - s), 1.0f);
        pooled[t * 4 + 0] = r.x * inv;
        pooled[t * 4 + 1] = r.y * inv;
        pooled[t * 4 + 2] = r.z * inv;
        pooled[t * 4 + 3] = r.w * inv;
    }
    __syncthreads();

    if (t < OC) {
        float a = 0.0f;
#pragma unroll 8
        for (int k = 0; k < CH; k++) a += pooled[k] * Wlin[k * OC + t];
        out[g * OC + t] = a;
    }
}

// ---------------- launch ----------------
extern "C" void kernel_launch(void* const* d_in, const int* in_sizes, int n_in,
                              void* d_out, int out_size, void* d_ws, size_t ws_size,
                              hipStream_t stream) {
    const float* x = (const float*)d_in[0];
    const int* ei = (const int*)d_in[1];
    const int* src = ei;
    const int* dst = ei + NE;
    const int* batch = (const int*)d_in[2];
    const float* W1 = (const float*)d_in[3];
    const float* b1 = (const float*)d_in[4];
    const float* W2 = (const float*)d_in[5];
    const float* b2 = (const float*)d_in[6];
    const float* W3 = (const float*)d_in[7];
    const float* b3 = (const float*)d_in[8];
    const float* Wlin = (const float*)d_in[9];
    float* out = (float*)d_out;

    char* ws = (char*)d_ws;
    unsigned short* Ha = (unsigned short*)ws;  ws += (size_t)NN * CH * 2;  // 19.2 MB
    unsigned short* Hb = (unsigned short*)ws;  ws += (size_t)NN * CH * 2;  // 19.2 MB
    unsigned short* Bb = (unsigned short*)ws;  ws += (size_t)NN * CH * 2;  // 19.2 MB
    float2* packed = (float2*)ws;   ws += (size_t)NE * 8;        // 6.4 MB
    unsigned short* WH = (unsigned short*)ws;  ws += 3 * CH * CH * 2;  // 55 KB
    unsigned short* WL = (unsigned short*)ws;  ws += 3 * CH * CH * 2;
    float* dinv = (float*)ws;       ws += NN * 4;
    int* off = (int*)ws;            ws += NN * 4;
    int* goff = (int*)ws;           ws += 272 * 4;       // NG+1, padded
    int* cnt = (int*)ws;            ws += (NN + 4) * 4;  // +gtot slot
    int* gtot = cnt + NN;
    int* slot = (int*)Bb;  // Bb dead until agg1 writes it; slot last read by k_build

    // init (zero cnt/gtot + W prep), then front (gemm1 || hist), offsets, build
    k_init<<<NBLK, 256, 0, stream>>>(cnt, W1, W2, W3, WH, WL);
    k_front<<<GBLK + NE / 256, 256, 0, stream>>>(x, WH, WL, Ha, dst, cnt, slot);
    k_offsets<<<NBLK, 256, 0, stream>>>(cnt, gtot, off, dinv, batch, goff);
    k_build<<<NE / 256, 256, 0, stream>>>(src, dst, off, slot, dinv, packed);

    const int ablk = (NN * 12 + 255) / 256;

    // layer 1 aggregate: Ha -> Bb (relu)
    k_aggregate<true><<<ablk, 256, 0, stream>>>(off, cnt, packed, dinv, b1, Ha, Bb);
    // layer 2: Bb -> Hb -> Bb (relu)
    k_gemm_bf16<<<GBLK, 256, 0, stream>>>(Bb, WH + CH * CH, WL + CH * CH, Hb);
    k_aggregate<true><<<ablk, 256, 0, stream>>>(off, cnt, packed, dinv, b2, Hb, Bb);
    // layer 3: Bb -> Ha -> Bb (no relu)
    k_gemm_bf16<<<GBLK, 256, 0, stream>>>(Bb, WH + 2 * CH * CH, WL + 2 * CH * CH, Ha);
    k_aggregate<false><<<ablk, 256, 0, stream>>>(off, cnt, packed, dinv, b3, Ha, Bb);

    // fused pool + linear
    k_pool_linear<<<NG, 384, 0, stream>>>(goff, Bb, Wlin, out);
}